// Round 8
// baseline (3913.248 us; speedup 1.0000x reference)
//
#include <hip/hip_runtime.h>

// LSTM B=1024 T=512 H=256 (input_size=1, output_size=1) on MI355X.
// R12: surgical on R4 (proven 1583us). R11 post-mortem: barrier-free flag
// sync REGRESSED (2770us) -- per-step lgkmcnt(0) drains + 7 flag polls are
// costlier than one barrier. Grid/regfile walls are final: 64 blk x 512 thr,
// 2 waves/SIMD, weights can't all be resident (512KB = whole CU RF).
// R4's 7400cy/step = busy ~4300 (MFMA 640, VALU 1160, LDS ~3300 incl 700cy
// INITG const reads) + ~3000 latency exposure. Three fixes:
//  1. gate consts -> 16 REGS (kills INITG LDS reads + step-head latency)
//  2. S-order stagger: waves 0-3 do S0->S1, waves 4-7 S1->S0. SIMD siblings
//     (w,w+4) anti-align: one in MFMA/LDS phase while other in GATES
//     (VALU/trans). Numerically identical (disjoint cols, c_st slots).
//  3. o-MFMAs FIRST in each group, refill sb right after -> o prefetch
//     distance 400->750cy; s_setprio(1) around MFMA cluster / (0) in GATES
//     (stagger creates the role diversity setprio needs, per T5).
// Rest identical to R4: i,f reg-resident (128 regs), g LDS (128KB),
// o L2-streamed via rotating 32-reg buffer, h bf16 LDS dbuf stride 264,
// one barrier/step.

#define HID 256
#define TT 512
#define BROWS 16
#define NBLK 64
#define THREADS 512
#define HPAD 264

typedef float v4f __attribute__((ext_vector_type(4)));
typedef unsigned int v4u __attribute__((ext_vector_type(4)));
typedef __bf16 v8bf __attribute__((ext_vector_type(8)));

__device__ __forceinline__ unsigned short f2bf(float f) {
    unsigned int u = __builtin_bit_cast(unsigned int, f);
    u += 0x7fffu + ((u >> 16) & 1u);   // RNE
    return (unsigned short)(u >> 16);
}
__device__ __forceinline__ float bf2f(unsigned short s) {
    unsigned int u = ((unsigned int)s) << 16;
    return __builtin_bit_cast(float, u);
}
__device__ __forceinline__ float fsigmoid(float x) {
    float e = exp2f(x * -1.44269504f);
    return __builtin_amdgcn_rcpf(1.0f + e);
}
__device__ __forceinline__ float ftanh(float x) {
    float e = exp2f(x * 2.88539008f);
    return 1.0f - 2.0f * __builtin_amdgcn_rcpf(1.0f + e);
}

// W_hh fp32 [1024][256] -> bf16 fragment order:
// Wbf[((Tn*8+kc)*64+lane)*8 + j] = bf16(W_hh[16*Tn+(lane&15)][32*kc+(lane>>4)*8+j])
__global__ void wconv_kernel(const float* __restrict__ Whh,
                             unsigned short* __restrict__ Wbf) {
    int tid = blockIdx.x * blockDim.x + threadIdx.x;   // 0..32767
    int lane = tid & 63;
    int frag = tid >> 6;
    int Tn = frag >> 3;
    int kc = frag & 7;
    int n  = Tn * 16 + (lane & 15);
    int kb = kc * 32 + (lane >> 4) * 8;
    const float* src = Whh + (size_t)n * HID + kb;
    unsigned short* dst = Wbf + (size_t)tid * 8;
#pragma unroll
    for (int j = 0; j < 8; ++j) dst[j] = f2bf(src[j]);
}

#define MFMA8(ACC, BARR, BOFF)                                               \
    _Pragma("unroll")                                                        \
    for (int kc = 0; kc < 8; ++kc)                                           \
        ACC = __builtin_amdgcn_mfma_f32_16x16x32_bf16(afrag[kc],             \
                  BARR[(BOFF) + kc], ACC, 0, 0, 0);

// LDS-resident g tile for this wave, slot = w*2 + S
#define LDSTILE(ACC, SLOT)                                                   \
    { v8bf bl_[8];                                                           \
      _Pragma("unroll")                                                      \
      for (int kc = 0; kc < 8; ++kc)                                         \
          bl_[kc] = __builtin_bit_cast(v8bf, *(const v4u*)(Wlds +            \
                      ((size_t)(((SLOT) * 8 + kc) * 64 + lane)) * 8));       \
      MFMA8(ACC, bl_, 0) }

// stream a tile by absolute tile index TN into SB
#define SLOADT(SB, TN)                                                       \
    _Pragma("unroll")                                                        \
    for (int kc = 0; kc < 8; ++kc)                                           \
        SB[kc] = __builtin_bit_cast(v8bf, *(const v4u*)(Wbf +                \
                   ((size_t)((TN) * 8 + kc) * 64 + lane) * 8));

#define GATES(S, AI, AF, AG, AO)                                             \
    _Pragma("unroll")                                                        \
    for (int r = 0; r < 4; ++r) {                                            \
        float gi = fsigmoid(AI[r]);                                          \
        float gf = fsigmoid(AF[r]);                                          \
        float gg = ftanh(AG[r]);                                             \
        float go = fsigmoid(AO[r]);                                          \
        float cn = gf * c_st[(S) * 4 + r] + gi * gg;                         \
        c_st[(S) * 4 + r] = cn;                                              \
        hn_[(quad * 4 + r) * HPAD + 16 * (w + 8 * (S)) + l4] =               \
            f2bf(go * ftanh(cn));                                            \
    }

// one gate-group: o first (consume prefetched sb), refill sb, then i/f/g,
// setprio around the MFMA cluster, GATES after.
#define GROUP(S, NEXTS)                                                      \
    { v4f ai, af2, ag, ao;                                                   \
      _Pragma("unroll")                                                      \
      for (int r = 0; r < 4; ++r) {                                          \
          ai[r]  = xv[r] * cw[S][0] + cb[S][0];                              \
          af2[r] = xv[r] * cw[S][1] + cb[S][1];                              \
          ag[r]  = xv[r] * cw[S][2] + cb[S][2];                              \
          ao[r]  = xv[r] * cw[S][3] + cb[S][3];                              \
      }                                                                      \
      __builtin_amdgcn_s_setprio(1);                                         \
      MFMA8(ao, sb, 0)                                                       \
      SLOADT(sb, 48 + w + 8 * (NEXTS))                                       \
      MFMA8(ai, wres, (S) * 16 + 0)                                          \
      MFMA8(af2, wres, (S) * 16 + 8)                                         \
      LDSTILE(ag, w * 2 + (S))                                               \
      __builtin_amdgcn_s_setprio(0);                                         \
      GATES(S, ai, af2, ag, ao)                                              \
    }

__global__ __launch_bounds__(THREADS, 1)
void lstm_kernel(const float* __restrict__ x,
                 const float* __restrict__ W_ih,
                 const float* __restrict__ b_ih,
                 const float* __restrict__ b_hh,
                 const float* __restrict__ W_lin,
                 const float* __restrict__ b_lin,
                 const unsigned short* __restrict__ Wbf,
                 float* __restrict__ out) {
    __shared__ __align__(16) unsigned short Wlds[16 * 8 * 64 * 8];   // 128 KB
    __shared__ __align__(16) unsigned short hbuf[2][BROWS * HPAD];   // 16.9 KB
    __shared__ float part[THREADS];                                  // 2 KB

    const int tid  = threadIdx.x;
    const int lane = tid & 63;
    const int w    = tid >> 6;      // wave 0..7
    const int l4   = lane & 15;
    const int quad = lane >> 4;
    const int r0   = blockIdx.x * BROWS;

    // h(0) = 0
    for (int i = tid; i < BROWS * HPAD; i += THREADS) hbuf[0][i] = 0;

    // register-resident tiles: i,f gates both S: idx (S*2+G), Tn = 16*G + w + 8*S
    v8bf wres[32];
#pragma unroll
    for (int S = 0; S < 2; ++S)
#pragma unroll
        for (int G = 0; G < 2; ++G) {
            int Tn = 16 * G + w + 8 * S;
#pragma unroll
            for (int kc = 0; kc < 8; ++kc)
                wres[(S * 2 + G) * 8 + kc] = __builtin_bit_cast(v8bf,
                    *(const v4u*)(Wbf + ((size_t)(Tn * 8 + kc) * 64 + lane) * 8));
        }
    // LDS-resident g-gate tiles: slot w*2+S <- Tn = 32 + w + 8*S
#pragma unroll
    for (int S = 0; S < 2; ++S) {
        int Tn = 32 + w + 8 * S;
        int slot = w * 2 + S;
#pragma unroll
        for (int kc = 0; kc < 8; ++kc) {
            v4u d = *(const v4u*)(Wbf + ((size_t)((Tn * 8 + kc) * 64 + lane)) * 8);
            *(v4u*)(Wlds + ((size_t)((slot * 8 + kc) * 64 + lane)) * 8) = d;
        }
    }

    // gate consts in registers (R12 fix 1): cw[S][g], cb[S][g]
    float cw[2][4], cb[2][4];
#pragma unroll
    for (int S = 0; S < 2; ++S) {
        int colS = 16 * (w + 8 * S) + l4;
#pragma unroll
        for (int g = 0; g < 4; ++g) {
            cw[S][g] = W_ih[g * 256 + colS];
            cb[S][g] = b_ih[g * 256 + colS] + b_hh[g * 256 + colS];
        }
    }

    __syncthreads();

    float c_st[8];
#pragma unroll
    for (int i = 0; i < 8; ++i) c_st[i] = 0.0f;

    // stagger (R12 fix 2): waves 0-3 first do S=0, waves 4-7 first do S=1
    // rotating stream buffer; prologue: o-tile of this wave's FIRST group
    v8bf sb[8];
    SLOADT(sb, 48 + w + ((w >> 2) << 3))

    float xv[4];
#pragma unroll
    for (int r = 0; r < 4; ++r)
        xv[r] = x[(size_t)(r0 + quad * 4 + r) * TT];

    int cur = 0;
    for (int t = 0; t < TT; ++t) {
        const unsigned short* hb = hbuf[cur];
        unsigned short* hn_ = hbuf[cur ^ 1];

        v8bf afrag[8];
        const unsigned short* hrow = hb + l4 * HPAD + quad * 8;
#pragma unroll
        for (int kc = 0; kc < 8; ++kc)
            afrag[kc] = __builtin_bit_cast(v8bf, *(const v4u*)(hrow + kc * 32));

        if (w < 4) {
            GROUP(0, 1)
            GROUP(1, 0)
        } else {
            GROUP(1, 0)
            GROUP(0, 1)
        }

        // x prefetch for t+1 (wraps harmlessly)
        {
            int tn = (t + 1) & (TT - 1);
#pragma unroll
            for (int r = 0; r < 4; ++r)
                xv[r] = x[(size_t)(r0 + quad * 4 + r) * TT + tn];
        }

        cur ^= 1;
        __syncthreads();
    }

    // Epilogue: out[b] = h_final . W_lin + b_lin
    {
        int rrow = tid >> 5, s5 = tid & 31;
        float p = 0.0f;
#pragma unroll
        for (int jj = 0; jj < 8; ++jj) {
            int j = s5 * 8 + jj;
            p += bf2f(hbuf[cur][rrow * HPAD + j]) * W_lin[j];
        }
        part[tid] = p;
    }
    __syncthreads();
    if (tid < 16) {
        float sum = 0.0f;
#pragma unroll
        for (int s = 0; s < 32; ++s) sum += part[tid * 32 + s];
        out[r0 + tid] = sum + b_lin[0];
    }
}

extern "C" void kernel_launch(void* const* d_in, const int* in_sizes, int n_in,
                              void* d_out, int out_size, void* d_ws, size_t ws_size,
                              hipStream_t stream) {
    const float* x     = (const float*)d_in[0];
    const float* W_ih  = (const float*)d_in[1];
    const float* W_hh  = (const float*)d_in[2];
    const float* b_ih  = (const float*)d_in[3];
    const float* b_hh  = (const float*)d_in[4];
    const float* W_lin = (const float*)d_in[5];
    const float* b_lin = (const float*)d_in[6];
    unsigned short* Wbf = (unsigned short*)d_ws;   // 512 KB

    wconv_kernel<<<128, 256, 0, stream>>>(W_hh, Wbf);
    lstm_kernel<<<NBLK, THREADS, 0, stream>>>(x, W_ih, b_ih, b_hh, W_lin, b_lin,
                                              Wbf, (float*)d_out);
}